// Round 18
// baseline (216.550 us; speedup 1.0000x reference)
//
#include <hip/hip_runtime.h>
#include <cstdint>
#include <cstddef>

#define IMGW 640
#define HPW  160
#define BATCH 2

typedef _Float16 h2v __attribute__((ext_vector_type(2)));
#if defined(__has_builtin)
#if __has_builtin(__builtin_amdgcn_fdot2)
#define HAVE_FDOT2 1
#endif
#endif

__device__ __forceinline__ float fdot2f(float a, float b, float c) {
#if HAVE_FDOT2
    return __builtin_amdgcn_fdot2(__builtin_bit_cast(h2v, a),
                                  __builtin_bit_cast(h2v, b), c, false);
#else
    h2v av = __builtin_bit_cast(h2v, a), bv = __builtin_bit_cast(h2v, b);
    return fmaf((float)av.x, (float)bv.x, fmaf((float)av.y, (float)bv.y, c));
#endif
}

__device__ __forceinline__ float packh2(float a, float b) {
    h2v p; p.x = (_Float16)a; p.y = (_Float16)b;
    return __builtin_bit_cast(float, p);
}

// tiny-|h| GELU: h*(0.5 + phi0*h*(1 - h^2/6)), clamp poly input to |h|<=1.
__device__ __forceinline__ float gelu_poly(float h) {
    float hc = fminf(fmaxf(h, -1.0f), 1.0f);
    float q = fmaf(hc * hc, -0.1666666667f, 1.0f);
    float r = fmaf(0.3989422804f * hc, q, 0.5f);
    return h * r;
}

__device__ __forceinline__ float fast_tanh(float t) {
    float u = __builtin_amdgcn_exp2f(2.8853900818f * t);    // e^{2t}
    return 1.0f - 2.0f * __builtin_amdgcn_rcpf(u + 1.0f);
}

__device__ __forceinline__ float wred64(float v) {
#pragma unroll
    for (int m = 1; m < 64; m <<= 1) v += __shfl_xor(v, m, 64);
    return v;
}

// ---------------------------------------------------------------------------
// Kernel 1: fold embed into ph_w1, pack per-channel weights as 16 dwords
// (f16 pairs + fp32 tail + bias_int). Also B1f border-bias table.
// ---------------------------------------------------------------------------
__global__ void fold_kernel(const float* __restrict__ ph_w1,
                            const float* __restrict__ embed_w,
                            const float* __restrict__ embed_b,
                            const float* __restrict__ ph_b1,
                            float* __restrict__ w1h,
                            float* __restrict__ B1f) {
    int e = blockIdx.x * 128 + threadIdx.x;
    if (e >= 96) return;
    float g[27];   // [k*3+c]
    float bf[9];
#pragma unroll
    for (int k = 0; k < 27; ++k) g[k] = 0.f;
#pragma unroll
    for (int k = 0; k < 9; ++k) bf[k] = 0.f;
    for (int c96 = 0; c96 < 96; ++c96) {
        const float* w = ph_w1 + e * 864 + c96 * 9;
        float e0 = embed_w[c96 * 3], e1 = embed_w[c96 * 3 + 1], e2 = embed_w[c96 * 3 + 2];
        float eb = embed_b[c96];
#pragma unroll
        for (int k = 0; k < 9; ++k) {
            float wk = w[k];
            g[k * 3 + 0] = fmaf(wk, e0, g[k * 3 + 0]);
            g[k * 3 + 1] = fmaf(wk, e1, g[k * 3 + 1]);
            g[k * 3 + 2] = fmaf(wk, e2, g[k * 3 + 2]);
            bf[k] = fmaf(wk, eb, bf[k]);
        }
    }
    float bi = ph_b1[e];
#pragma unroll
    for (int k = 0; k < 9; ++k) { B1f[e * 9 + k] = bf[k]; bi += bf[k]; }
    float* dst = w1h + e * 16;
#pragma unroll
    for (int c = 0; c < 3; ++c)
#pragma unroll
        for (int j = 0; j < 4; ++j)
            dst[c * 4 + j] = packh2(g[(2 * j) * 3 + c], g[(2 * j + 1) * 3 + c]);
    dst[12] = packh2(g[8 * 3 + 0], g[8 * 3 + 1]);
    dst[13] = g[8 * 3 + 2];
    dst[14] = bi;
    dst[15] = 0.f;
}

// ---------------------------------------------------------------------------
// Kernel 2 (FUSED, 512 threads): conv1+GELU+conv2 -> params in LDS -> token
// sampling + LN. INTRA-BLOCK channel split: waves 0-3 do channels 0-47,
// waves 4-7 do 48-95, same 16x16 pixel tile (staging SHARED, unlike the
// cross-block NG split that duplicated it — R3/R11 lesson). Per-thread loop
// work halves, wave count doubles -> occupancy cap 100% (8 waves/block,
// 4 blocks/CU wave-limited). Token phase: 2 tokens per wave.
// ---------------------------------------------------------------------------
__global__ __launch_bounds__(512) void fused_kernel(
    const float* __restrict__ x,
    const float* __restrict__ w1h,
    const float* __restrict__ B1f,
    const float* __restrict__ ph_b1,
    const float* __restrict__ ph_w2,
    const float* __restrict__ ph_b2,
    const float* __restrict__ ew,
    const float* __restrict__ eb,
    const float* __restrict__ lnw,
    const float* __restrict__ lnb,
    float* __restrict__ out) {
    __shared__ float xs[3 * 18 * 18];     // 3888 B: 16x16 tile + 1px halo
    __shared__ float w2l[16 * 293];       // 18752 B: [pi][e*3+ch], stride 293
    __shared__ float pp[2][16][3];        // 384 B: per-group per-patch sums

    int bid = blockIdx.x;                 // 2 * 40 * 40
    int b = bid / 1600;
    int rem = bid - b * 1600;
    int th = rem / 40, tw = rem - th * 40;
    int y0 = th * 16, x0 = tw * 16;
    int tid = threadIdx.x;

    const float* xb = x + (size_t)b * 3 * 409600;
    for (int l = tid; l < 972; l += 512) {
        int c = l / 324;
        int r2 = l - c * 324;
        int ry = r2 / 18, rx = r2 - ry * 18;
        int gy = y0 - 1 + ry, gx = x0 - 1 + rx;
        float v = 0.f;
        if (gy >= 0 && gy < IMGW && gx >= 0 && gx < IMGW)
            v = xb[c * 409600 + gy * 640 + gx];
        xs[l] = v;
    }
    for (int l = tid; l < 4608; l += 512) {
        int ch = l / 1536;
        int r2 = l - ch * 1536;
        int e = r2 >> 4, pi = r2 & 15;
        w2l[pi * 293 + e * 3 + ch] = ph_w2[l];
    }
    __syncthreads();

    int wv = tid >> 6;                    // 0..7
    int gsel = wv >> 2;                   // channel group 0/1
    int w = wv & 3;                       // patch row
    int lane = tid & 63;
    int q = lane >> 4, pi = lane & 15;
    int py = pi >> 2, px = pi & 3;
    int ty = w * 4 + py, tx = q * 4 + px;

    // load 3x3x3 window and pack to f16 pairs (order matches fold layout)
    float xpk[13];
    float x8c2;
    {
        float win[27];
#pragma unroll
        for (int c = 0; c < 3; ++c)
#pragma unroll
            for (int dy = 0; dy < 3; ++dy)
#pragma unroll
                for (int dx = 0; dx < 3; ++dx)
                    win[c * 9 + dy * 3 + dx] = xs[c * 324 + (ty + dy) * 18 + (tx + dx)];
#pragma unroll
        for (int c = 0; c < 3; ++c)
#pragma unroll
            for (int j = 0; j < 4; ++j)
                xpk[c * 4 + j] = packh2(win[c * 9 + 2 * j], win[c * 9 + 2 * j + 1]);
        xpk[12] = packh2(win[8], win[9 + 8]);
        x8c2 = win[18 + 8];
    }
#pragma unroll
    for (int k = 0; k < 13; ++k) asm volatile("" : "+v"(xpk[k]));
    asm volatile("" : "+v"(x8c2));

    float s0 = 0.f, s1 = 0.f, s2 = 0.f;
    const int wbase = pi * 293;
    bool borderBlk = (th == 0) || (tw == 0) || (th == 39) || (tw == 39);
    int e0 = gsel * 48, e1 = e0 + 48;

    if (!borderBlk) {
        for (int e = e0; e < e1; ++e) {
            const float4* u4 = reinterpret_cast<const float4*>(w1h + e * 16);
            float4 A = u4[0], B = u4[1], C = u4[2], D = u4[3];
            float accA = fdot2f(A.w, xpk[3], D.z);
            accA = fdot2f(A.z, xpk[2], accA);
            accA = fdot2f(A.y, xpk[1], accA);
            accA = fdot2f(A.x, xpk[0], accA);
            float accB = fdot2f(D.x, xpk[12], D.y * x8c2);
            accB = fdot2f(B.w, xpk[7], accB);
            accB = fdot2f(B.z, xpk[6], accB);
            accB = fdot2f(B.y, xpk[5], accB);
            accB = fdot2f(B.x, xpk[4], accB);
            float accC = fdot2f(C.w, xpk[11], 0.f);
            accC = fdot2f(C.z, xpk[10], accC);
            accC = fdot2f(C.y, xpk[9], accC);
            accC = fdot2f(C.x, xpk[8], accC);
            float h = (accA + accB) + accC;
            float g = gelu_poly(h);
            s0 = fmaf(w2l[wbase + e * 3 + 0], g, s0);
            s1 = fmaf(w2l[wbase + e * 3 + 1], g, s1);
            s2 = fmaf(w2l[wbase + e * 3 + 2], g, s2);
        }
    } else {
        float m[9];
        int gy0 = y0 + ty - 1, gx0 = x0 + tx - 1;
#pragma unroll
        for (int ky = 0; ky < 3; ++ky)
#pragma unroll
            for (int kx = 0; kx < 3; ++kx) {
                int iy = gy0 + ky, ix = gx0 + kx;
                m[ky * 3 + kx] = (iy >= 0 && iy < IMGW && ix >= 0 && ix < IMGW) ? 1.f : 0.f;
            }
        for (int e = e0; e < e1; ++e) {
            const float4* u4 = reinterpret_cast<const float4*>(w1h + e * 16);
            float4 A = u4[0], B = u4[1], C = u4[2], D = u4[3];
            float bb = ph_b1[e];
#pragma unroll
            for (int k = 0; k < 9; ++k)
                bb = fmaf(m[k], B1f[e * 9 + k], bb);
            float accA = fdot2f(A.w, xpk[3], bb);
            accA = fdot2f(A.z, xpk[2], accA);
            accA = fdot2f(A.y, xpk[1], accA);
            accA = fdot2f(A.x, xpk[0], accA);
            float accB = fdot2f(D.x, xpk[12], D.y * x8c2);
            accB = fdot2f(B.w, xpk[7], accB);
            accB = fdot2f(B.z, xpk[6], accB);
            accB = fdot2f(B.y, xpk[5], accB);
            accB = fdot2f(B.x, xpk[4], accB);
            float accC = fdot2f(C.w, xpk[11], 0.f);
            accC = fdot2f(C.z, xpk[10], accC);
            accC = fdot2f(C.y, xpk[9], accC);
            accC = fdot2f(C.x, xpk[8], accC);
            float h = (accA + accB) + accC;
            float g = gelu_poly(h);
            s0 = fmaf(w2l[wbase + e * 3 + 0], g, s0);
            s1 = fmaf(w2l[wbase + e * 3 + 1], g, s1);
            s2 = fmaf(w2l[wbase + e * 3 + 2], g, s2);
        }
    }

    // reduce conv2 over the 16 pixels of each patch (one 16-lane segment)
#pragma unroll
    for (int mm = 1; mm < 16; mm <<= 1) {
        s0 += __shfl_xor(s0, mm, 16);
        s1 += __shfl_xor(s1, mm, 16);
        s2 += __shfl_xor(s2, mm, 16);
    }

    if (pi == 0) {
        int p = w * 4 + q;
        pp[gsel][p][0] = s0;
        pp[gsel][p][1] = s1;
        pp[gsel][p][2] = s2;
    }
    __syncthreads();

    // ---------------- token phase: wave wv handles tokens wv*2, wv*2+1 ------
    float pb0 = ph_b2[0], pb1 = ph_b2[1], pb2v = ph_b2[2];
    const float* xbp = x + (size_t)b * 3 * 409600;
#pragma unroll
    for (int t = 0; t < 2; ++t) {
        int p = wv * 2 + t;
        float dx = pp[0][p][0] + pp[1][p][0] + pb0;
        float dy = pp[0][p][1] + pp[1][p][1] + pb1;
        float ls = pp[0][p][2] + pp[1][p][2] + pb2v;
        int hp = th * 4 + (p >> 2), wp2 = tw * 4 + (p & 3);
        size_t idx = (size_t)hp * 160 + wp2;

        float mx = 2.0f * fast_tanh(dx);
        float my = 2.0f * fast_tanh(dy);
        float s = __builtin_amdgcn_exp2f(1.4426950409f * fast_tanh(ls));
        s = fminf(fmaxf(s, 0.5f), 2.0f);
        float half = 2.0f * s;
        float cx = (float)(wp2 * 4) + 2.0f;
        float cy = (float)(hp * 4) + 2.0f;
        float x1b = fminf(fmaxf(cx + mx - half, 0.f), 639.f);
        float x2b = fminf(fmaxf(cx + mx + half, 0.f), 639.f);
        float y1b = fminf(fmaxf(cy + my - half, 0.f), 639.f);
        float y2b = fminf(fmaxf(cy + my + half, 0.f), 639.f);

        int ssi = lane >> 2, stap = lane & 3;
        int spy = ssi >> 2, spx = ssi & 3;
        float xsf = x1b + (x2b - x1b) * ((float)spx * (1.0f / 3.0f));
        float ysf = y1b + (y2b - y1b) * ((float)spy * (1.0f / 3.0f));
        float x0f = floorf(xsf), y0f = floorf(ysf);
        float wx = xsf - x0f, wy = ysf - y0f;
        int xi0 = min(max((int)x0f, 0), 639);
        int yi0 = min(max((int)y0f, 0), 639);
        int xi1 = min(xi0 + 1, 639);
        int yi1 = min(yi0 + 1, 639);
        int xx = (stap & 1) ? xi1 : xi0;
        int yy = (stap & 2) ? yi1 : yi0;
        float wgt = ((stap & 1) ? wx : 1.f - wx) * ((stap & 2) ? wy : 1.f - wy);

        int off = yy * 640 + xx;
        float a0 = wgt * xbp[off];
        float a1 = wgt * xbp[409600 + off];
        float a2 = wgt * xbp[819200 + off];

        a0 = wred64(a0) * (1.0f / 16.0f);
        a1 = wred64(a1) * (1.0f / 16.0f);
        a2 = wred64(a2) * (1.0f / 16.0f);

        float t1 = eb[lane] + ew[lane * 3] * a0 + ew[lane * 3 + 1] * a1 + ew[lane * 3 + 2] * a2;
        float t2 = 0.f;
        if (lane < 32) {
            int d = 64 + lane;
            t2 = eb[d] + ew[d * 3] * a0 + ew[d * 3 + 1] * a1 + ew[d * 3 + 2] * a2;
        }
        float sum = t1 + ((lane < 32) ? t2 : 0.f);
        float mu = wred64(sum) * (1.0f / 96.0f);
        float d1 = t1 - mu, d2 = t2 - mu;
        float qq = d1 * d1 + ((lane < 32) ? d2 * d2 : 0.f);
        float var = wred64(qq) * (1.0f / 96.0f);
        float rs = 1.0f / sqrtf(var + 1e-5f);

        size_t ob = ((size_t)b * 25600 + idx) * 96;
        out[ob + lane] = d1 * rs * lnw[lane] + lnb[lane];
        if (lane < 32) {
            int d = 64 + lane;
            out[ob + d] = d2 * rs * lnw[d] + lnb[d];
        }
        if (lane == 0) {
            out[(size_t)4915200 + (size_t)b * 25600 + idx] = s;
        }
    }
}

// ---------------------------------------------------------------------------
extern "C" void kernel_launch(void* const* d_in, const int* in_sizes, int n_in,
                              void* d_out, int out_size, void* d_ws, size_t ws_size,
                              hipStream_t stream) {
    const float* x       = (const float*)d_in[0];
    const float* embed_w = (const float*)d_in[1];
    const float* embed_b = (const float*)d_in[2];
    const float* ph_w1   = (const float*)d_in[3];
    const float* ph_b1   = (const float*)d_in[4];
    const float* ph_w2   = (const float*)d_in[5];
    const float* ph_b2   = (const float*)d_in[6];
    const float* ln_w    = (const float*)d_in[7];
    const float* ln_b    = (const float*)d_in[8];

    float* ws = (float*)d_ws;
    float* w1h = ws;                 // 96*16 = 1536 floats (packed weights)
    float* B1f = ws + 1536;          // 864

    fold_kernel<<<1, 128, 0, stream>>>(ph_w1, embed_w, embed_b, ph_b1, w1h, B1f);
    fused_kernel<<<3200, 512, 0, stream>>>(x, w1h, B1f, ph_b1, ph_w2, ph_b2,
                                           embed_w, embed_b, ln_w, ln_b,
                                           (float*)d_out);
}

// Round 19
// 116.745 us; speedup vs baseline: 1.8549x; 1.8549x over previous
//
#include <hip/hip_runtime.h>
#include <cstdint>
#include <cstddef>

#define IMGW 640
#define HPW  160
#define BATCH 2

typedef _Float16 h2v __attribute__((ext_vector_type(2)));
#if defined(__has_builtin)
#if __has_builtin(__builtin_amdgcn_fdot2)
#define HAVE_FDOT2 1
#endif
#endif

// R10/R16's verified form: builtin-guarded fdot2.
__device__ __forceinline__ float fdot2f(float a, float b, float c) {
#if HAVE_FDOT2
    return __builtin_amdgcn_fdot2(__builtin_bit_cast(h2v, a),
                                  __builtin_bit_cast(h2v, b), c, false);
#else
    h2v av = __builtin_bit_cast(h2v, a), bv = __builtin_bit_cast(h2v, b);
    return fmaf((float)av.x, (float)bv.x, fmaf((float)av.y, (float)bv.y, c));
#endif
}

__device__ __forceinline__ float packh2(float a, float b) {
    h2v p; p.x = (_Float16)a; p.y = (_Float16)b;
    return __builtin_bit_cast(float, p);
}

// tiny-|h| GELU: h*(0.5 + phi0*h*(1 - h^2/6)), clamp poly input to |h|<=1.
__device__ __forceinline__ float gelu_poly(float h) {
    float hc = fminf(fmaxf(h, -1.0f), 1.0f);
    float q = fmaf(hc * hc, -0.1666666667f, 1.0f);
    float r = fmaf(0.3989422804f * hc, q, 0.5f);
    return h * r;
}

__device__ __forceinline__ float fast_tanh(float t) {
    float u = __builtin_amdgcn_exp2f(2.8853900818f * t);    // e^{2t}
    return 1.0f - 2.0f * __builtin_amdgcn_rcpf(u + 1.0f);
}

__device__ __forceinline__ float wred64(float v) {
#pragma unroll
    for (int m = 1; m < 64; m <<= 1) v += __shfl_xor(v, m, 64);
    return v;
}

// ---------------------------------------------------------------------------
// Kernel 1: fold embed into ph_w1, pack per-channel weights as 16 dwords
// (f16 pairs + fp32 tail + bias_int). Also B1f border-bias table.
// ---------------------------------------------------------------------------
__global__ void fold_kernel(const float* __restrict__ ph_w1,
                            const float* __restrict__ embed_w,
                            const float* __restrict__ embed_b,
                            const float* __restrict__ ph_b1,
                            float* __restrict__ w1h,
                            float* __restrict__ B1f) {
    int e = blockIdx.x * 128 + threadIdx.x;
    if (e >= 96) return;
    float g[27];   // [k*3+c]
    float bf[9];
#pragma unroll
    for (int k = 0; k < 27; ++k) g[k] = 0.f;
#pragma unroll
    for (int k = 0; k < 9; ++k) bf[k] = 0.f;
    for (int c96 = 0; c96 < 96; ++c96) {
        const float* w = ph_w1 + e * 864 + c96 * 9;
        float e0 = embed_w[c96 * 3], e1 = embed_w[c96 * 3 + 1], e2 = embed_w[c96 * 3 + 2];
        float eb = embed_b[c96];
#pragma unroll
        for (int k = 0; k < 9; ++k) {
            float wk = w[k];
            g[k * 3 + 0] = fmaf(wk, e0, g[k * 3 + 0]);
            g[k * 3 + 1] = fmaf(wk, e1, g[k * 3 + 1]);
            g[k * 3 + 2] = fmaf(wk, e2, g[k * 3 + 2]);
            bf[k] = fmaf(wk, eb, bf[k]);
        }
    }
    float bi = ph_b1[e];
#pragma unroll
    for (int k = 0; k < 9; ++k) { B1f[e * 9 + k] = bf[k]; bi += bf[k]; }
    float* dst = w1h + e * 16;
#pragma unroll
    for (int c = 0; c < 3; ++c)
#pragma unroll
        for (int j = 0; j < 4; ++j)
            dst[c * 4 + j] = packh2(g[(2 * j) * 3 + c], g[(2 * j + 1) * 3 + c]);
    dst[12] = packh2(g[8 * 3 + 0], g[8 * 3 + 1]);
    dst[13] = g[8 * 3 + 2];
    dst[14] = bi;
    dst[15] = 0.f;
}

// ---------------------------------------------------------------------------
// Kernel 2 (FUSED): conv1(folded fdot2) + GELU + conv2  ->  params in LDS
// -> coords + bilinear sample + embed matvec + LayerNorm, all in one block.
// Block = 16x16 px = 16 patches = 16 tokens, 256 threads. (R16 verbatim —
// R17's 512-thread split hit the VGPR=32 allocator cliff and spilled the
// pinned window to scratch, 2x regression.)
// ---------------------------------------------------------------------------
__global__ __launch_bounds__(256) void fused_kernel(
    const float* __restrict__ x,
    const float* __restrict__ w1h,
    const float* __restrict__ B1f,
    const float* __restrict__ ph_b1,
    const float* __restrict__ ph_w2,
    const float* __restrict__ ph_b2,
    const float* __restrict__ ew,
    const float* __restrict__ eb,
    const float* __restrict__ lnw,
    const float* __restrict__ lnb,
    float* __restrict__ out) {
    __shared__ float xs[3 * 18 * 18];     // 3888 B: 16x16 tile + 1px halo
    __shared__ float w2l[16 * 293];       // 18752 B: [pi][e*3+ch], stride 293
    __shared__ float pp[16][3];           // 192 B: per-patch (dx,dy,ls) sums

    int bid = blockIdx.x;                 // 2 * 40 * 40
    int b = bid / 1600;
    int rem = bid - b * 1600;
    int th = rem / 40, tw = rem - th * 40;
    int y0 = th * 16, x0 = tw * 16;
    int tid = threadIdx.x;

    const float* xb = x + (size_t)b * 3 * 409600;
    for (int l = tid; l < 972; l += 256) {
        int c = l / 324;
        int r2 = l - c * 324;
        int ry = r2 / 18, rx = r2 - ry * 18;
        int gy = y0 - 1 + ry, gx = x0 - 1 + rx;
        float v = 0.f;
        if (gy >= 0 && gy < IMGW && gx >= 0 && gx < IMGW)
            v = xb[c * 409600 + gy * 640 + gx];
        xs[l] = v;
    }
    for (int l = tid; l < 4608; l += 256) {
        int ch = l / 1536;
        int r2 = l - ch * 1536;
        int e = r2 >> 4, pi = r2 & 15;
        w2l[pi * 293 + e * 3 + ch] = ph_w2[l];
    }
    __syncthreads();

    int w = tid >> 6, lane = tid & 63;
    int q = lane >> 4, pi = lane & 15;
    int py = pi >> 2, px = pi & 3;
    int ty = w * 4 + py, tx = q * 4 + px;

    // load 3x3x3 window and pack to f16 pairs (order matches fold layout)
    float xpk[13];
    float x8c2;
    {
        float win[27];
#pragma unroll
        for (int c = 0; c < 3; ++c)
#pragma unroll
            for (int dy = 0; dy < 3; ++dy)
#pragma unroll
                for (int dx = 0; dx < 3; ++dx)
                    win[c * 9 + dy * 3 + dx] = xs[c * 324 + (ty + dy) * 18 + (tx + dx)];
#pragma unroll
        for (int c = 0; c < 3; ++c)
#pragma unroll
            for (int j = 0; j < 4; ++j)
                xpk[c * 4 + j] = packh2(win[c * 9 + 2 * j], win[c * 9 + 2 * j + 1]);
        xpk[12] = packh2(win[8], win[9 + 8]);
        x8c2 = win[18 + 8];
    }
#pragma unroll
    for (int k = 0; k < 13; ++k) asm volatile("" : "+v"(xpk[k]));
    asm volatile("" : "+v"(x8c2));

    float s0 = 0.f, s1 = 0.f, s2 = 0.f;
    const int wbase = pi * 293;
    bool borderBlk = (th == 0) || (tw == 0) || (th == 39) || (tw == 39);

    if (!borderBlk) {
        for (int e = 0; e < 96; ++e) {
            const float4* u4 = reinterpret_cast<const float4*>(w1h + e * 16);
            float4 A = u4[0], B = u4[1], C = u4[2], D = u4[3];
            float accA = fdot2f(A.w, xpk[3], D.z);
            accA = fdot2f(A.z, xpk[2], accA);
            accA = fdot2f(A.y, xpk[1], accA);
            accA = fdot2f(A.x, xpk[0], accA);
            float accB = fdot2f(D.x, xpk[12], D.y * x8c2);
            accB = fdot2f(B.w, xpk[7], accB);
            accB = fdot2f(B.z, xpk[6], accB);
            accB = fdot2f(B.y, xpk[5], accB);
            accB = fdot2f(B.x, xpk[4], accB);
            float accC = fdot2f(C.w, xpk[11], 0.f);
            accC = fdot2f(C.z, xpk[10], accC);
            accC = fdot2f(C.y, xpk[9], accC);
            accC = fdot2f(C.x, xpk[8], accC);
            float h = (accA + accB) + accC;
            float g = gelu_poly(h);
            s0 = fmaf(w2l[wbase + e * 3 + 0], g, s0);
            s1 = fmaf(w2l[wbase + e * 3 + 1], g, s1);
            s2 = fmaf(w2l[wbase + e * 3 + 2], g, s2);
        }
    } else {
        float m[9];
        int gy0 = y0 + ty - 1, gx0 = x0 + tx - 1;
#pragma unroll
        for (int ky = 0; ky < 3; ++ky)
#pragma unroll
            for (int kx = 0; kx < 3; ++kx) {
                int iy = gy0 + ky, ix = gx0 + kx;
                m[ky * 3 + kx] = (iy >= 0 && iy < IMGW && ix >= 0 && ix < IMGW) ? 1.f : 0.f;
            }
        for (int e = 0; e < 96; ++e) {
            const float4* u4 = reinterpret_cast<const float4*>(w1h + e * 16);
            float4 A = u4[0], B = u4[1], C = u4[2], D = u4[3];
            float bb = ph_b1[e];
#pragma unroll
            for (int k = 0; k < 9; ++k)
                bb = fmaf(m[k], B1f[e * 9 + k], bb);
            float accA = fdot2f(A.w, xpk[3], bb);
            accA = fdot2f(A.z, xpk[2], accA);
            accA = fdot2f(A.y, xpk[1], accA);
            accA = fdot2f(A.x, xpk[0], accA);
            float accB = fdot2f(D.x, xpk[12], D.y * x8c2);
            accB = fdot2f(B.w, xpk[7], accB);
            accB = fdot2f(B.z, xpk[6], accB);
            accB = fdot2f(B.y, xpk[5], accB);
            accB = fdot2f(B.x, xpk[4], accB);
            float accC = fdot2f(C.w, xpk[11], 0.f);
            accC = fdot2f(C.z, xpk[10], accC);
            accC = fdot2f(C.y, xpk[9], accC);
            accC = fdot2f(C.x, xpk[8], accC);
            float h = (accA + accB) + accC;
            float g = gelu_poly(h);
            s0 = fmaf(w2l[wbase + e * 3 + 0], g, s0);
            s1 = fmaf(w2l[wbase + e * 3 + 1], g, s1);
            s2 = fmaf(w2l[wbase + e * 3 + 2], g, s2);
        }
    }

    // reduce conv2 over the 16 pixels of each patch (one 16-lane segment)
#pragma unroll
    for (int mm = 1; mm < 16; mm <<= 1) {
        s0 += __shfl_xor(s0, mm, 16);
        s1 += __shfl_xor(s1, mm, 16);
        s2 += __shfl_xor(s2, mm, 16);
    }

    if (pi == 0) {
        int p = w * 4 + q;
        pp[p][0] = s0;
        pp[p][1] = s1;
        pp[p][2] = s2;
    }
    __syncthreads();

    // ---------------- token phase: wave w handles patches w*4 .. w*4+3 ------
    float pb0 = ph_b2[0], pb1 = ph_b2[1], pb2v = ph_b2[2];
    const float* xbp = x + (size_t)b * 3 * 409600;
#pragma unroll
    for (int t = 0; t < 4; ++t) {
        int p = w * 4 + t;
        float dx = pp[p][0] + pb0;
        float dy = pp[p][1] + pb1;
        float ls = pp[p][2] + pb2v;
        int hp = th * 4 + (p >> 2), wp2 = tw * 4 + (p & 3);
        size_t idx = (size_t)hp * 160 + wp2;

        float mx = 2.0f * fast_tanh(dx);
        float my = 2.0f * fast_tanh(dy);
        float s = __builtin_amdgcn_exp2f(1.4426950409f * fast_tanh(ls));
        s = fminf(fmaxf(s, 0.5f), 2.0f);
        float half = 2.0f * s;
        float cx = (float)(wp2 * 4) + 2.0f;
        float cy = (float)(hp * 4) + 2.0f;
        float x1b = fminf(fmaxf(cx + mx - half, 0.f), 639.f);
        float x2b = fminf(fmaxf(cx + mx + half, 0.f), 639.f);
        float y1b = fminf(fmaxf(cy + my - half, 0.f), 639.f);
        float y2b = fminf(fmaxf(cy + my + half, 0.f), 639.f);

        int ssi = lane >> 2, stap = lane & 3;
        int spy = ssi >> 2, spx = ssi & 3;
        float xsf = x1b + (x2b - x1b) * ((float)spx * (1.0f / 3.0f));
        float ysf = y1b + (y2b - y1b) * ((float)spy * (1.0f / 3.0f));
        float x0f = floorf(xsf), y0f = floorf(ysf);
        float wx = xsf - x0f, wy = ysf - y0f;
        int xi0 = min(max((int)x0f, 0), 639);
        int yi0 = min(max((int)y0f, 0), 639);
        int xi1 = min(xi0 + 1, 639);
        int yi1 = min(yi0 + 1, 639);
        int xx = (stap & 1) ? xi1 : xi0;
        int yy = (stap & 2) ? yi1 : yi0;
        float wgt = ((stap & 1) ? wx : 1.f - wx) * ((stap & 2) ? wy : 1.f - wy);

        int off = yy * 640 + xx;
        float a0 = wgt * xbp[off];
        float a1 = wgt * xbp[409600 + off];
        float a2 = wgt * xbp[819200 + off];

        a0 = wred64(a0) * (1.0f / 16.0f);
        a1 = wred64(a1) * (1.0f / 16.0f);
        a2 = wred64(a2) * (1.0f / 16.0f);

        float t1 = eb[lane] + ew[lane * 3] * a0 + ew[lane * 3 + 1] * a1 + ew[lane * 3 + 2] * a2;
        float t2 = 0.f;
        if (lane < 32) {
            int d = 64 + lane;
            t2 = eb[d] + ew[d * 3] * a0 + ew[d * 3 + 1] * a1 + ew[d * 3 + 2] * a2;
        }
        float sum = t1 + ((lane < 32) ? t2 : 0.f);
        float mu = wred64(sum) * (1.0f / 96.0f);
        float d1 = t1 - mu, d2 = t2 - mu;
        float qq = d1 * d1 + ((lane < 32) ? d2 * d2 : 0.f);
        float var = wred64(qq) * (1.0f / 96.0f);
        float rs = 1.0f / sqrtf(var + 1e-5f);

        size_t ob = ((size_t)b * 25600 + idx) * 96;
        out[ob + lane] = d1 * rs * lnw[lane] + lnb[lane];
        if (lane < 32) {
            int d = 64 + lane;
            out[ob + d] = d2 * rs * lnw[d] + lnb[d];
        }
        if (lane == 0) {
            out[(size_t)4915200 + (size_t)b * 25600 + idx] = s;
        }
    }
}

// ---------------------------------------------------------------------------
extern "C" void kernel_launch(void* const* d_in, const int* in_sizes, int n_in,
                              void* d_out, int out_size, void* d_ws, size_t ws_size,
                              hipStream_t stream) {
    const float* x       = (const float*)d_in[0];
    const float* embed_w = (const float*)d_in[1];
    const float* embed_b = (const float*)d_in[2];
    const float* ph_w1   = (const float*)d_in[3];
    const float* ph_b1   = (const float*)d_in[4];
    const float* ph_w2   = (const float*)d_in[5];
    const float* ph_b2   = (const float*)d_in[6];
    const float* ln_w    = (const float*)d_in[7];
    const float* ln_b    = (const float*)d_in[8];

    float* ws = (float*)d_ws;
    float* w1h = ws;                 // 96*16 = 1536 floats (packed weights)
    float* B1f = ws + 1536;          // 864

    fold_kernel<<<1, 128, 0, stream>>>(ph_w1, embed_w, embed_b, ph_b1, w1h, B1f);
    fused_kernel<<<3200, 256, 0, stream>>>(x, w1h, B1f, ph_b1, ph_w2, ph_b2,
                                           embed_w, embed_b, ln_w, ln_b,
                                           (float*)d_out);
}